// Round 5
// baseline (414.672 us; speedup 1.0000x reference)
//
#include <hip/hip_runtime.h>
#include <hip/hip_fp16.h>

typedef _Float16 half8 __attribute__((ext_vector_type(8)));
typedef __attribute__((ext_vector_type(4)))  float floatx4;
typedef __attribute__((ext_vector_type(16))) float floatx16;

#define BB 32
#define CC 256
#define OO 256
#define KS 7
#define HH 31
#define WW 31
#define HO 25
#define PP 625
#define SS 49

#define SLAB_PITCH 36        // ushort elems per pos row: 32 ci + 4 pad = 72 B
                             // (18-bank stride: ~2-way conflict on b128, free)
#define SLAB_ROWS  310       // 64-p tile spans <= 10 x-rows; 10 x 31 = 310
#define P_TILE 64
#define NPX 10               // ceil(625/64)
#define KPD 20               // klds pitch in dwords (16 half2 + 4 pad)

// wt4 layout: [s][cb][kh][o][16ci]  (elems per (s,cb) = 2*256*16 = 8192)
#define WT4_ELEMS  ((size_t)SS * 8 * 2 * CC * 16)        // 3,211,264
#define WT4_BYTES  (WT4_ELEMS * 2)                       // 6,422,528

static __device__ __forceinline__ unsigned pk2h(float lo, float hi) {
    __half2 h = __floats2half2_rn(lo, hi);    // v_cvt_pkrtz_f16_f32
    unsigned r;
    __builtin_memcpy(&r, &h, sizeof(r));
    return r;
}
static __device__ __forceinline__ unsigned mulh2(unsigned a, unsigned b) {
    __half2 x, y;
    __builtin_memcpy(&x, &a, 4); __builtin_memcpy(&y, &b, 4);
    __half2 r = __hmul2(x, y);                // v_pk_mul_f16
    unsigned u;
    __builtin_memcpy(&u, &r, 4);
    return u;
}
// modulated A-fragment: 8 fp16 = w[j] * k[j] via 4x v_pk_mul_f16
static __device__ __forceinline__ half8 mod8(uint4 w, uint4 k) {
    uint4 r;
    r.x = mulh2(w.x, k.x); r.y = mulh2(w.y, k.y);
    r.z = mulh2(w.z, k.z); r.w = mulh2(w.w, k.w);
    return __builtin_bit_cast(half8, r);
}

// ---------------------------------------------------------------------------
// Prepass: w[o][c][s] f32 -> wt4[s][cb][kh][o][16] fp16. Grid 392 = (s*8+cb).
// ---------------------------------------------------------------------------
__global__ __launch_bounds__(256) void repack_w(const float* __restrict__ w,
                                                unsigned short* __restrict__ wt4) {
    const int bid = blockIdx.x;           // = s*8 + cb
    const int s = bid >> 3, cb = bid & 7;
    const int o = threadIdx.x;
    const float* src = w + ((size_t)o * CC + cb * 32) * SS + s;
    float v[32];
#pragma unroll
    for (int ci = 0; ci < 32; ++ci) v[ci] = src[(size_t)ci * SS];
#pragma unroll
    for (int kh = 0; kh < 2; ++kh) {
        unsigned short* dst = wt4 + ((size_t)bid * 2 + kh) * (CC * 16) + o * 16;
        uint4 p0, p1;
        p0.x = pk2h(v[kh*16+0], v[kh*16+1]);  p0.y = pk2h(v[kh*16+2], v[kh*16+3]);
        p0.z = pk2h(v[kh*16+4], v[kh*16+5]);  p0.w = pk2h(v[kh*16+6], v[kh*16+7]);
        p1.x = pk2h(v[kh*16+8], v[kh*16+9]);  p1.y = pk2h(v[kh*16+10], v[kh*16+11]);
        p1.z = pk2h(v[kh*16+12], v[kh*16+13]); p1.w = pk2h(v[kh*16+14], v[kh*16+15]);
        *(uint4*)(dst)     = p0;
        *(uint4*)(dst + 8) = p1;
    }
}

// ---------------------------------------------------------------------------
// Fused main: block = 128o x 64p of one batch, 512 threads = 8 waves
// (2 wo x 2 wp x 2 kw). Wave = 64o x 32p, s-half per kw.
// Per s-step per wave: 4 global uint4 A (wt4, L2-pinned per XCD),
// 2 ds b128 B + 2 ds b128 k-broadcast (halved LDS/MFMA vs R4),
// 16 v_pk_mul_f16 modulation, 4x mfma_32x32x16_f16 into acc[2].
// Grid 640 = 32b x 2oy x 10px; lb(512,6): 3 blocks/CU -> up to 24 waves/CU
// (75% occ; R4's measured limiter was 27% occ + 6 LDS reads per 4 MFMA).
// kw-pair reduced via LDS in 2 wp-rounds (R2-verified pattern).
// ---------------------------------------------------------------------------
__global__ __launch_bounds__(512, 6) void dwconv_fused(
        const float* __restrict__ x, const unsigned short* __restrict__ wt4,
        const float* __restrict__ kern, const float* __restrict__ bias,
        float* __restrict__ out) {
    __shared__ unsigned short slab[SLAB_ROWS * SLAB_PITCH];   // 22320 B
    __shared__ unsigned klds[SS * KPD];                       // 3920 B

    const int tid = threadIdx.x;
    const int id = blockIdx.x;
    // oy on XCD parity: each XCD's L2 holds one 3.2 MB wt4 o-slice
    const int oy = id & 1;
    const int m = id >> 1;                    // 0..319
    const int b = m / NPX, px = m - (m / NPX) * NPX;

    const int p0 = px * P_TILE;
    const int h0 = p0 / HO;
    const int pmax = (p0 + P_TILE - 1 < PP - 1) ? p0 + P_TILE - 1 : PP - 1;
    const int rows = pmax / HO - h0 + 7;          // <= 10
    const int npos = rows * WW;

    const int lane = tid & 63, wid = tid >> 6;    // wid 0..7
    const int wo = wid & 1, wp = (wid >> 1) & 1, kw = wid >> 2;
    const int l32 = lane & 31, half = lane >> 5;

    // B-fragment LDS offset (ushort elems) for this wave's 32-p subtile
    int bOff;
    {
        int p = p0 + wp * 32 + l32;
        if (p > PP - 1) p = PP - 1;               // clamp; store guarded later
        int h = p / HO, ww_ = p - h * HO;
        bOff = ((h - h0) * WW + ww_) * SLAB_PITCH + half * 8;
    }

    const int s0 = kw ? 25 : 0;
    const int ns = kw ? 24 : 25;

    // A base: rows (oy*128 + wo*64 + oh*32 + l32); oh -> +512, kh -> +4096;
    // per-s stride 65536; per-cb offset cb*8192
    const unsigned short* wbase = wt4
        + (size_t)(oy * 128 + wo * 64 + l32) * 16 + half * 8;

    floatx16 acc[2];
#pragma unroll
    for (int oh = 0; oh < 2; ++oh)
#pragma unroll
        for (int rr = 0; rr < 16; ++rr) acc[oh][rr] = 0.f;

    for (int cb = 0; cb < 8; ++cb) {
        __syncthreads();   // prior compute done: slab/klds safe to overwrite
        // ---- stage x slab: slab[pos][ci] fp16, 8 waves x 4 channels ----
        {
            const float* xsrc = x + ((size_t)(b * CC + cb * 32 + wid * 4)) * (HH * WW)
                                  + h0 * WW;
#pragma unroll
            for (int it = 0; it < 5; ++it) {
                int pos = lane + it * 64;
                if (pos < npos) {
                    float v0 = xsrc[pos];
                    float v1 = xsrc[(size_t)(HH * WW) + pos];
                    float v2 = xsrc[(size_t)(2 * HH * WW) + pos];
                    float v3 = xsrc[(size_t)(3 * HH * WW) + pos];
                    uint2 pkt;
                    pkt.x = pk2h(v0, v1); pkt.y = pk2h(v2, v3);
                    *(uint2*)(slab + pos * SLAB_PITCH + wid * 4) = pkt;
                }
            }
        }
        // ---- stage k table: klds[s][16 half2] for this (b, cb) ----
        {
            const float* ksrc = kern + ((size_t)(b * CC + cb * 32)) * SS;
#pragma unroll
            for (int it = 0; it < 2; ++it) {
                int f = tid + it * 512;
                if (f < 16 * SS) {
                    int s = f >> 4, pr = f & 15;
                    float v0 = ksrc[(size_t)(pr * 2) * SS + s];
                    float v1 = ksrc[(size_t)(pr * 2 + 1) * SS + s];
                    klds[s * KPD + pr] = pk2h(v0, v1);
                }
            }
        }
        __syncthreads();

        const unsigned short* aptr = wbase + (size_t)(s0 * 8 + cb) * 8192;

        int kk = kw ? 3 : 0, ll = kw ? 4 : 0;     // s0 = kk*7 + ll
        for (int si = 0; si < ns; ++si) {
            uint4 wa0 = *(const uint4*)(aptr);            // oh0 kh0
            uint4 wa1 = *(const uint4*)(aptr + 512);      // oh1 kh0
            uint4 wa2 = *(const uint4*)(aptr + 4096);     // oh0 kh1
            uint4 wa3 = *(const uint4*)(aptr + 4608);     // oh1 kh1

            const unsigned* kp = klds + (size_t)(s0 + si) * KPD;
            uint4 kv0 = *(const uint4*)(kp + half * 4);        // kh0 ci
            uint4 kv1 = *(const uint4*)(kp + 8 + half * 4);    // kh1 ci

            const unsigned short* slabS = slab + (kk * WW + ll) * SLAB_PITCH;
            half8 b0 = *(const half8*)(slabS + bOff);          // kh0
            half8 b1 = *(const half8*)(slabS + bOff + 16);     // kh1

            half8 a0 = mod8(wa0, kv0);
            half8 a1 = mod8(wa1, kv0);
            half8 a2 = mod8(wa2, kv1);
            half8 a3 = mod8(wa3, kv1);

            acc[0] = __builtin_amdgcn_mfma_f32_32x32x16_f16(a0, b0, acc[0], 0, 0, 0);
            acc[1] = __builtin_amdgcn_mfma_f32_32x32x16_f16(a1, b0, acc[1], 0, 0, 0);
            acc[0] = __builtin_amdgcn_mfma_f32_32x32x16_f16(a2, b1, acc[0], 0, 0, 0);
            acc[1] = __builtin_amdgcn_mfma_f32_32x32x16_f16(a3, b1, acc[1], 0, 0, 0);

            aptr += 65536;
            if (++ll == KS) { ll = 0; ++kk; }
        }
    }

    // ---- epilogue: kw-pair reduction via LDS (reuse slab), 2 wp-rounds ----
    // C/D 32x32 mapping: col = l32 (p), row = (reg&3) + 8*(reg>>2) + 4*half (o)
    float* red = (float*)slab;
    for (int round = 0; round < 2; ++round) {
        __syncthreads();
        if (kw == 1 && wp == round) {
#pragma unroll
            for (int oh = 0; oh < 2; ++oh)
#pragma unroll
                for (int c = 0; c < 4; ++c) {
                    floatx4 v4 = {acc[oh][4*c+0], acc[oh][4*c+1],
                                  acc[oh][4*c+2], acc[oh][4*c+3]};
                    *(floatx4*)(red + wo * 2176 + l32 * 68 + oh * 32 + c * 8 + 4 * half) = v4;
                }
        }
        __syncthreads();
        if (kw == 0 && wp == round) {
            const int pout = p0 + wp * 32 + l32;
#pragma unroll
            for (int oh = 0; oh < 2; ++oh)
#pragma unroll
                for (int c = 0; c < 4; ++c) {
                    const int ob = oy * 128 + wo * 64 + oh * 32 + c * 8 + 4 * half;
                    const float4 bv = *(const float4*)(bias + ob);
                    floatx4 v4 = *(const floatx4*)(red + wo * 2176 + l32 * 68
                                                   + oh * 32 + c * 8 + 4 * half);
                    if (pout < PP) {
                        out[((size_t)(b * OO + ob + 0)) * PP + pout] = acc[oh][4*c+0] + v4[0] + bv.x;
                        out[((size_t)(b * OO + ob + 1)) * PP + pout] = acc[oh][4*c+1] + v4[1] + bv.y;
                        out[((size_t)(b * OO + ob + 2)) * PP + pout] = acc[oh][4*c+2] + v4[2] + bv.z;
                        out[((size_t)(b * OO + ob + 3)) * PP + pout] = acc[oh][4*c+3] + v4[3] + bv.w;
                    }
                }
        }
    }
}

// ---------------------------------------------------------------------------
// Last-resort fallback: naive but correct (ws too small for wt4).
// ---------------------------------------------------------------------------
__global__ __launch_bounds__(256) void dwconv_naive(
        const float* __restrict__ x, const float* __restrict__ kern,
        const float* __restrict__ w, const float* __restrict__ bias,
        float* __restrict__ out) {
    const int idx = blockIdx.x * 256 + threadIdx.x;
    if (idx >= BB * OO * PP) return;
    const int p = idx % PP;
    const int o = (idx / PP) % OO;
    const int b = idx / (PP * OO);
    const int h = p / HO;
    const int wq = p - h * HO;
    float acc = 0.f;
    for (int c = 0; c < CC; ++c) {
        const float* xp = x + ((size_t)(b * CC + c)) * (HH * WW) + h * WW + wq;
        const float* kp = kern + ((size_t)b * CC + c) * SS;
        const float* wp = w + ((size_t)o * CC + c) * SS;
#pragma unroll
        for (int s = 0; s < SS; ++s) {
            const int kk = s / KS;
            const int ll = s - kk * KS;
            acc += xp[kk * WW + ll] * kp[s] * wp[s];
        }
    }
    out[idx] = acc + bias[o];
}

extern "C" void kernel_launch(void* const* d_in, const int* in_sizes, int n_in,
                              void* d_out, int out_size, void* d_ws, size_t ws_size,
                              hipStream_t stream) {
    const float* x    = (const float*)d_in[0];
    const float* kern = (const float*)d_in[1];
    const float* w    = (const float*)d_in[2];
    const float* bias = (const float*)d_in[3];
    float* out = (float*)d_out;

    if (ws_size >= WT4_BYTES) {
        unsigned short* wt4 = (unsigned short*)d_ws;
        repack_w<<<dim3(SS * 8), dim3(256), 0, stream>>>(w, wt4);
        dwconv_fused<<<dim3(640), dim3(512), 0, stream>>>(x, wt4, kern, bias, out);
    } else {
        const int total = BB * OO * PP;
        dwconv_naive<<<dim3((total + 255) / 256), dim3(256), 0, stream>>>(
            x, kern, w, bias, out);
    }
}